// Round 2
// baseline (2897.479 us; speedup 1.0000x reference)
//
#include <hip/hip_runtime.h>

// SparseResidualBlock: gather-conv(27,32x32) -> BN+ReLU -> gather-conv -> BN -> +feat, ReLU
// bf16 MFMA (16x16x32), fp32 accumulate; BN stats from fp32 accumulators.
//
// R2: non-temporal hints on all STREAMING traffic (nbr reads, conv out stores,
// elementwise in/out) so the 128-MB gather table stays Infinity-Cache-resident.
// Gathers and the stores that produce the gather table remain normal (cached).
// (R1 compile fix: nontemporal builtins need ext_vector types, not HIP float4.)

typedef __attribute__((ext_vector_type(8))) short bf16x8;
typedef __attribute__((ext_vector_type(8))) unsigned short ushort8;
typedef __attribute__((ext_vector_type(4))) float f32x4;

#define NPTS 2000000

__device__ __forceinline__ unsigned short f2bf(float f) {
    union { float f; unsigned u; } x; x.f = f;
    unsigned r = x.u + 0x7fffu + ((x.u >> 16) & 1u);   // round-to-nearest-even
    return (unsigned short)(r >> 16);
}
__device__ __forceinline__ float bf2f(unsigned short h) {
    union { unsigned u; float f; } x; x.u = ((unsigned)h) << 16;
    return x.f;
}

// ---- feat fp32 -> bf16 (64M elems, 8 per thread) -------------------------
__global__ void cvt_feat(const float* __restrict__ in, unsigned short* __restrict__ out) {
    size_t i = (size_t)blockIdx.x * 256 + threadIdx.x;      // vec8 index, 8,000,000 total
    const f32x4* inv = (const f32x4*)in;
    f32x4 u = __builtin_nontemporal_load(inv + i * 2);      // feat: streamed, don't pollute L3
    f32x4 v = __builtin_nontemporal_load(inv + i * 2 + 1);
    ushort8 o;
    o[0] = f2bf(u[0]); o[1] = f2bf(u[1]); o[2] = f2bf(u[2]); o[3] = f2bf(u[3]);
    o[4] = f2bf(v[0]); o[5] = f2bf(v[1]); o[6] = f2bf(v[2]); o[7] = f2bf(v[3]);
    ((ushort8*)out)[i] = o;                                 // gather table: keep cached
}

// ---- W [27][cin][cout] fp32 -> Wt [27][cout][cin] bf16 -------------------
__global__ void w_prep(const float* __restrict__ W1, const float* __restrict__ W2,
                       unsigned short* __restrict__ W1t, unsigned short* __restrict__ W2t) {
    int t = blockIdx.x * 256 + threadIdx.x;                 // 55296 threads exactly
    const float* W = (t < 27648) ? W1 : W2;
    unsigned short* Wt = (t < 27648) ? W1t : W2t;
    int rr = (t < 27648) ? t : t - 27648;
    int k = rr >> 10;
    int rem = rr & 1023;
    int co = rem >> 5, ci = rem & 31;
    Wt[rr] = f2bf(W[k * 1024 + ci * 32 + co]);
}

// ---- gather-conv: out[p] = sum_k x[nbr[p][k]] @ W[k], bf16 MFMA ----------
// block = 256 thr (4 waves), group = 320 points (wave: 5 sub-tiles of 16)
__global__ __launch_bounds__(256, 4) void conv_mfma(
    const unsigned short* __restrict__ x,     // N x 32 bf16
    const int* __restrict__ nbr,              // N x 27
    const unsigned short* __restrict__ Wt,    // 27 x 32(co) x 32(ci) bf16
    unsigned short* __restrict__ out,         // N x 32 bf16
    float* __restrict__ stats)                // sum[32], sumsq[32]
{
    __shared__ int nbr_lds[320 * 27];
    const int tid  = threadIdx.x;
    const int lane = tid & 63;
    const int wave = tid >> 6;
    const int m = lane & 15;          // A row / out channel (acc0)
    const int q = lane >> 4;          // quad: k-chunk / out-row group
    const int p_base = blockIdx.x * 320;

    for (int i = tid; i < 320 * 27; i += 256)
        nbr_lds[i] = __builtin_nontemporal_load(nbr + (size_t)p_base * 27 + i);  // streamed
    __syncthreads();

    const bf16x8* xv = (const bf16x8*)x;
    const bf16x8* wv = (const bf16x8*)Wt;

    f32x4 acc[5][2];
    f32x4 zero = {0.f, 0.f, 0.f, 0.f};
    #pragma unroll
    for (int s = 0; s < 5; ++s) { acc[s][0] = zero; acc[s][1] = zero; }

    const int wp = wave * 80;
    const int nbase = (wp + m) * 27;

    #pragma unroll 1
    for (int k = 0; k < 27; ++k) {
        // B frag: lane holds Wt[k][n=m(+16)][ci = q*8 .. q*8+7], contiguous 16B
        bf16x8 b0 = wv[k * 128 + m * 4 + q];
        bf16x8 b1 = wv[k * 128 + 64 + m * 4 + q];
        #pragma unroll
        for (int s = 0; s < 5; ++s) {
            int idx = nbr_lds[nbase + s * 432 + k];
            // A frag: lane holds x[idx][q*8 .. q*8+7] — one dwordx4 gather (cached: L3-resident)
            bf16x8 a = xv[(unsigned)idx * 4u + q];
            acc[s][0] = __builtin_amdgcn_mfma_f32_16x16x32_bf16(a, b0, acc[s][0], 0, 0, 0);
            acc[s][1] = __builtin_amdgcn_mfma_f32_16x16x32_bf16(a, b1, acc[s][1], 0, 0, 0);
        }
    }

    // epilogue: store bf16 + accumulate BN stats from fp32 accs
    float sum0 = 0.f, sq0 = 0.f, sum1 = 0.f, sq1 = 0.f;
    #pragma unroll
    for (int s = 0; s < 5; ++s) {
        #pragma unroll
        for (int r = 0; r < 4; ++r) {
            float v0 = acc[s][0][r], v1 = acc[s][1][r];
            sum0 += v0; sq0 += v0 * v0;
            sum1 += v1; sq1 += v1 * v1;
            size_t p = (size_t)(p_base + wp + s * 16 + q * 4 + r);   // C/D row
            __builtin_nontemporal_store(f2bf(v0), &out[p * 32 + m]);        // streamed out
            __builtin_nontemporal_store(f2bf(v1), &out[p * 32 + 16 + m]);
        }
    }
    sum0 += __shfl_xor(sum0, 16); sum0 += __shfl_xor(sum0, 32);
    sq0  += __shfl_xor(sq0, 16);  sq0  += __shfl_xor(sq0, 32);
    sum1 += __shfl_xor(sum1, 16); sum1 += __shfl_xor(sum1, 32);
    sq1  += __shfl_xor(sq1, 16);  sq1  += __shfl_xor(sq1, 32);
    if (lane < 16) {
        atomicAdd(&stats[m],      sum0);
        atomicAdd(&stats[32 + m], sq0);
        atomicAdd(&stats[16 + m], sum1);
        atomicAdd(&stats[48 + m], sq1);
    }
}

// ---- BN stats -> per-channel affine (a, shift) ---------------------------
__global__ void finalize(const float* __restrict__ stats, const float* __restrict__ g,
                         const float* __restrict__ b, float* __restrict__ affine) {
    int c = threadIdx.x;
    if (c < 32) {
        const float invN = 1.0f / 2000000.0f;
        float mean = stats[c] * invN;
        float var  = stats[32 + c] * invN - mean * mean;
        float a = g[c] * rsqrtf(var + 1e-4f);
        affine[c] = a;
        affine[32 + c] = b[c] - mean * a;
    }
}

// ---- y = bf16(relu(x*a + sh)) -------------------------------------------
__global__ void bnrelu(const unsigned short* __restrict__ in, const float* __restrict__ affine,
                       unsigned short* __restrict__ out) {
    size_t i = (size_t)blockIdx.x * 256 + threadIdx.x;      // vec8 index
    int c0 = ((int)i & 3) * 8;
    f32x4 a0 = *(const f32x4*)(affine + c0);
    f32x4 a1 = *(const f32x4*)(affine + c0 + 4);
    f32x4 s0 = *(const f32x4*)(affine + 32 + c0);
    f32x4 s1 = *(const f32x4*)(affine + 32 + c0 + 4);
    float av[8] = {a0[0], a0[1], a0[2], a0[3], a1[0], a1[1], a1[2], a1[3]};
    float sv[8] = {s0[0], s0[1], s0[2], s0[3], s1[0], s1[1], s1[2], s1[3]};
    ushort8 v = __builtin_nontemporal_load((const ushort8*)in + i);   // tmp1: streamed once
    ushort8 o;
    #pragma unroll
    for (int j = 0; j < 8; ++j) {
        float t = bf2f(v[j]) * av[j] + sv[j];
        o[j] = f2bf(t > 0.f ? t : 0.f);
    }
    ((ushort8*)out)[i] = o;                                 // gather table for conv2: cached
}

// ---- out = relu(x*a + sh + feat), fp32 ----------------------------------
__global__ void final_k(const unsigned short* __restrict__ tmp2, const float* __restrict__ affine,
                        const float* __restrict__ feat, float* __restrict__ out) {
    size_t i = (size_t)blockIdx.x * 256 + threadIdx.x;      // vec8 index
    int c0 = ((int)i & 3) * 8;
    f32x4 a0 = *(const f32x4*)(affine + c0);
    f32x4 a1 = *(const f32x4*)(affine + c0 + 4);
    f32x4 s0 = *(const f32x4*)(affine + 32 + c0);
    f32x4 s1 = *(const f32x4*)(affine + 32 + c0 + 4);
    float av[8] = {a0[0], a0[1], a0[2], a0[3], a1[0], a1[1], a1[2], a1[3]};
    float sv[8] = {s0[0], s0[1], s0[2], s0[3], s1[0], s1[1], s1[2], s1[3]};
    ushort8 v = __builtin_nontemporal_load((const ushort8*)tmp2 + i);   // streamed
    const f32x4* fv4 = (const f32x4*)feat;
    f32x4 f0 = __builtin_nontemporal_load(fv4 + i * 2);                 // streamed
    f32x4 f1 = __builtin_nontemporal_load(fv4 + i * 2 + 1);
    float fv[8] = {f0[0], f0[1], f0[2], f0[3], f1[0], f1[1], f1[2], f1[3]};
    float r[8];
    #pragma unroll
    for (int j = 0; j < 8; ++j) {
        float t = bf2f(v[j]) * av[j] + sv[j] + fv[j];
        r[j] = t > 0.f ? t : 0.f;
    }
    f32x4 o0 = {r[0], r[1], r[2], r[3]};
    f32x4 o1 = {r[4], r[5], r[6], r[7]};
    f32x4* ov = (f32x4*)out;
    __builtin_nontemporal_store(o0, ov + i * 2);                        // streamed out
    __builtin_nontemporal_store(o1, ov + i * 2 + 1);
}

extern "C" void kernel_launch(void* const* d_in, const int* in_sizes, int n_in,
                              void* d_out, int out_size, void* d_ws, size_t ws_size,
                              hipStream_t stream) {
    const float* feat = (const float*)d_in[0];
    const int*   nbr  = (const int*)d_in[1];
    const float* W1   = (const float*)d_in[2];
    const float* g1   = (const float*)d_in[3];
    const float* b1   = (const float*)d_in[4];
    const float* W2   = (const float*)d_in[5];
    const float* g2   = (const float*)d_in[6];
    const float* b2   = (const float*)d_in[7];
    float* out = (float*)d_out;

    // workspace map: [stats1 64f | stats2 64f | aff1 64f | aff2 64f | W1t | W2t | pad to 128K | bufA 128MB | bufB 128MB]
    float* stats1 = (float*)d_ws;
    float* stats2 = stats1 + 64;
    float* aff1   = stats1 + 128;
    float* aff2   = stats1 + 192;
    unsigned short* W1t = (unsigned short*)(stats1 + 256);
    unsigned short* W2t = W1t + 27648;
    unsigned short* bufA = (unsigned short*)((char*)d_ws + (1 << 17));
    unsigned short* bufB = bufA + (size_t)64000000;

    hipMemsetAsync(d_ws, 0, 512, stream);                        // zero stats1+stats2

    cvt_feat<<<31250, 256, 0, stream>>>(feat, bufA);             // feat -> bf16
    w_prep<<<216, 256, 0, stream>>>(W1, W2, W1t, W2t);           // W -> bf16 [k][co][ci]

    conv_mfma<<<6250, 256, 0, stream>>>(bufA, nbr, W1t, bufB, stats1);   // conv1 -> tmp1 + stats1
    finalize<<<1, 64, 0, stream>>>(stats1, g1, b1, aff1);
    bnrelu<<<31250, 256, 0, stream>>>(bufB, aff1, bufA);         // y1 = relu(bn1(tmp1))

    conv_mfma<<<6250, 256, 0, stream>>>(bufA, nbr, W2t, bufB, stats2);   // conv2 -> tmp2 + stats2
    finalize<<<1, 64, 0, stream>>>(stats2, g2, b2, aff2);
    final_k<<<31250, 256, 0, stream>>>(bufB, aff2, feat, out);   // relu(bn2(tmp2) + feat)
}

// Round 3
// 2785.975 us; speedup vs baseline: 1.0400x; 1.0400x over previous
//
#include <hip/hip_runtime.h>

// SparseResidualBlock: gather-conv(27,32x32) -> BN+ReLU -> gather-conv -> BN -> +feat, ReLU
// bf16 MFMA (16x16x32), fp32 accumulate; BN stats from fp32 accumulators.
//
// R3: NT hints reverted (R2: no FETCH change, write-through hurt stores).
// conv_mfma k-loop is now depth-2 software-pipelined: while MFMAs consume
// tile k, the 5 row-gathers + 2 W-frag loads for k+1 are in flight.
// Theory: conv is gather-latency-bound (VGPR=52 => ~1-2 gathers in flight);
// doubling per-wave MLP should move L2-miss BW from 3.2 toward 5+ TB/s.

typedef __attribute__((ext_vector_type(8))) short bf16x8;
typedef __attribute__((ext_vector_type(8))) unsigned short ushort8;
typedef __attribute__((ext_vector_type(4))) float f32x4;

#define NPTS 2000000

__device__ __forceinline__ unsigned short f2bf(float f) {
    union { float f; unsigned u; } x; x.f = f;
    unsigned r = x.u + 0x7fffu + ((x.u >> 16) & 1u);   // round-to-nearest-even
    return (unsigned short)(r >> 16);
}
__device__ __forceinline__ float bf2f(unsigned short h) {
    union { unsigned u; float f; } x; x.u = ((unsigned)h) << 16;
    return x.f;
}

// ---- feat fp32 -> bf16 (64M elems, 8 per thread) -------------------------
__global__ void cvt_feat(const float* __restrict__ in, unsigned short* __restrict__ out) {
    size_t i = (size_t)blockIdx.x * 256 + threadIdx.x;      // vec8 index, 8,000,000 total
    float4 u = ((const float4*)in)[i * 2];
    float4 v = ((const float4*)in)[i * 2 + 1];
    ushort8 o;
    o[0] = f2bf(u.x); o[1] = f2bf(u.y); o[2] = f2bf(u.z); o[3] = f2bf(u.w);
    o[4] = f2bf(v.x); o[5] = f2bf(v.y); o[6] = f2bf(v.z); o[7] = f2bf(v.w);
    ((ushort8*)out)[i] = o;
}

// ---- W [27][cin][cout] fp32 -> Wt [27][cout][cin] bf16 -------------------
__global__ void w_prep(const float* __restrict__ W1, const float* __restrict__ W2,
                       unsigned short* __restrict__ W1t, unsigned short* __restrict__ W2t) {
    int t = blockIdx.x * 256 + threadIdx.x;                 // 55296 threads exactly
    const float* W = (t < 27648) ? W1 : W2;
    unsigned short* Wt = (t < 27648) ? W1t : W2t;
    int rr = (t < 27648) ? t : t - 27648;
    int k = rr >> 10;
    int rem = rr & 1023;
    int co = rem >> 5, ci = rem & 31;
    Wt[rr] = f2bf(W[k * 1024 + ci * 32 + co]);
}

// ---- gather-conv: out[p] = sum_k x[nbr[p][k]] @ W[k], bf16 MFMA ----------
// block = 256 thr (4 waves), group = 320 points (wave: 5 sub-tiles of 16)
__global__ __launch_bounds__(256, 4) void conv_mfma(
    const unsigned short* __restrict__ x,     // N x 32 bf16
    const int* __restrict__ nbr,              // N x 27
    const unsigned short* __restrict__ Wt,    // 27 x 32(co) x 32(ci) bf16
    unsigned short* __restrict__ out,         // N x 32 bf16
    float* __restrict__ stats)                // sum[32], sumsq[32]
{
    __shared__ int nbr_lds[320 * 27];
    const int tid  = threadIdx.x;
    const int lane = tid & 63;
    const int wave = tid >> 6;
    const int m = lane & 15;          // A row / out channel (acc0)
    const int q = lane >> 4;          // quad: k-chunk / out-row group
    const int p_base = blockIdx.x * 320;

    for (int i = tid; i < 320 * 27; i += 256)
        nbr_lds[i] = nbr[(size_t)p_base * 27 + i];
    __syncthreads();

    const bf16x8* xv = (const bf16x8*)x;
    const bf16x8* wv = (const bf16x8*)Wt;

    f32x4 acc[5][2];
    f32x4 zero = {0.f, 0.f, 0.f, 0.f};
    #pragma unroll
    for (int s = 0; s < 5; ++s) { acc[s][0] = zero; acc[s][1] = zero; }

    const int wp = wave * 80;
    const int nbase = (wp + m) * 27;

    // ---- depth-2 software pipeline over k ----
    bf16x8 aA[5], aB[5];
    bf16x8 bA0, bA1, bB0, bB1;

    // prologue: issue k=0
    bA0 = wv[m * 4 + q];
    bA1 = wv[64 + m * 4 + q];
    #pragma unroll
    for (int s = 0; s < 5; ++s)
        aA[s] = xv[(unsigned)nbr_lds[nbase + s * 432] * 4u + q];

    #pragma unroll 1
    for (int k = 0; k < 26; k += 2) {
        // issue k+1 into B (stays in flight while A computes)
        bB0 = wv[(k + 1) * 128 + m * 4 + q];
        bB1 = wv[(k + 1) * 128 + 64 + m * 4 + q];
        #pragma unroll
        for (int s = 0; s < 5; ++s)
            aB[s] = xv[(unsigned)nbr_lds[nbase + s * 432 + k + 1] * 4u + q];
        // compute k from A
        #pragma unroll
        for (int s = 0; s < 5; ++s) {
            acc[s][0] = __builtin_amdgcn_mfma_f32_16x16x32_bf16(aA[s], bA0, acc[s][0], 0, 0, 0);
            acc[s][1] = __builtin_amdgcn_mfma_f32_16x16x32_bf16(aA[s], bA1, acc[s][1], 0, 0, 0);
        }
        // issue k+2 into A (k max 24 -> k+2 max 26, always valid)
        bA0 = wv[(k + 2) * 128 + m * 4 + q];
        bA1 = wv[(k + 2) * 128 + 64 + m * 4 + q];
        #pragma unroll
        for (int s = 0; s < 5; ++s)
            aA[s] = xv[(unsigned)nbr_lds[nbase + s * 432 + k + 2] * 4u + q];
        // compute k+1 from B
        #pragma unroll
        for (int s = 0; s < 5; ++s) {
            acc[s][0] = __builtin_amdgcn_mfma_f32_16x16x32_bf16(aB[s], bB0, acc[s][0], 0, 0, 0);
            acc[s][1] = __builtin_amdgcn_mfma_f32_16x16x32_bf16(aB[s], bB1, acc[s][1], 0, 0, 0);
        }
    }
    // epilogue: k=26 from A
    #pragma unroll
    for (int s = 0; s < 5; ++s) {
        acc[s][0] = __builtin_amdgcn_mfma_f32_16x16x32_bf16(aA[s], bA0, acc[s][0], 0, 0, 0);
        acc[s][1] = __builtin_amdgcn_mfma_f32_16x16x32_bf16(aA[s], bA1, acc[s][1], 0, 0, 0);
    }

    // epilogue: store bf16 + accumulate BN stats from fp32 accs
    float sum0 = 0.f, sq0 = 0.f, sum1 = 0.f, sq1 = 0.f;
    #pragma unroll
    for (int s = 0; s < 5; ++s) {
        #pragma unroll
        for (int r = 0; r < 4; ++r) {
            float v0 = acc[s][0][r], v1 = acc[s][1][r];
            sum0 += v0; sq0 += v0 * v0;
            sum1 += v1; sq1 += v1 * v1;
            size_t p = (size_t)(p_base + wp + s * 16 + q * 4 + r);   // C/D row
            out[p * 32 + m]      = f2bf(v0);                          // C/D col
            out[p * 32 + 16 + m] = f2bf(v1);
        }
    }
    sum0 += __shfl_xor(sum0, 16); sum0 += __shfl_xor(sum0, 32);
    sq0  += __shfl_xor(sq0, 16);  sq0  += __shfl_xor(sq0, 32);
    sum1 += __shfl_xor(sum1, 16); sum1 += __shfl_xor(sum1, 32);
    sq1  += __shfl_xor(sq1, 16);  sq1  += __shfl_xor(sq1, 32);
    if (lane < 16) {
        atomicAdd(&stats[m],      sum0);
        atomicAdd(&stats[32 + m], sq0);
        atomicAdd(&stats[16 + m], sum1);
        atomicAdd(&stats[48 + m], sq1);
    }
}

// ---- BN stats -> per-channel affine (a, shift) ---------------------------
__global__ void finalize(const float* __restrict__ stats, const float* __restrict__ g,
                         const float* __restrict__ b, float* __restrict__ affine) {
    int c = threadIdx.x;
    if (c < 32) {
        const float invN = 1.0f / 2000000.0f;
        float mean = stats[c] * invN;
        float var  = stats[32 + c] * invN - mean * mean;
        float a = g[c] * rsqrtf(var + 1e-4f);
        affine[c] = a;
        affine[32 + c] = b[c] - mean * a;
    }
}

// ---- y = bf16(relu(x*a + sh)) -------------------------------------------
__global__ void bnrelu(const unsigned short* __restrict__ in, const float* __restrict__ affine,
                       unsigned short* __restrict__ out) {
    size_t i = (size_t)blockIdx.x * 256 + threadIdx.x;      // vec8 index
    int c0 = ((int)i & 3) * 8;
    float4 a0 = *(const float4*)(affine + c0);
    float4 a1 = *(const float4*)(affine + c0 + 4);
    float4 s0 = *(const float4*)(affine + 32 + c0);
    float4 s1 = *(const float4*)(affine + 32 + c0 + 4);
    float av[8] = {a0.x, a0.y, a0.z, a0.w, a1.x, a1.y, a1.z, a1.w};
    float sv[8] = {s0.x, s0.y, s0.z, s0.w, s1.x, s1.y, s1.z, s1.w};
    ushort8 v = ((const ushort8*)in)[i];
    ushort8 o;
    #pragma unroll
    for (int j = 0; j < 8; ++j) {
        float t = bf2f(v[j]) * av[j] + sv[j];
        o[j] = f2bf(t > 0.f ? t : 0.f);
    }
    ((ushort8*)out)[i] = o;
}

// ---- out = relu(x*a + sh + feat), fp32 ----------------------------------
__global__ void final_k(const unsigned short* __restrict__ tmp2, const float* __restrict__ affine,
                        const float* __restrict__ feat, float* __restrict__ out) {
    size_t i = (size_t)blockIdx.x * 256 + threadIdx.x;      // vec8 index
    int c0 = ((int)i & 3) * 8;
    float4 a0 = *(const float4*)(affine + c0);
    float4 a1 = *(const float4*)(affine + c0 + 4);
    float4 s0 = *(const float4*)(affine + 32 + c0);
    float4 s1 = *(const float4*)(affine + 32 + c0 + 4);
    float av[8] = {a0.x, a0.y, a0.z, a0.w, a1.x, a1.y, a1.z, a1.w};
    float sv[8] = {s0.x, s0.y, s0.z, s0.w, s1.x, s1.y, s1.z, s1.w};
    ushort8 v = ((const ushort8*)tmp2)[i];
    float4 f0 = ((const float4*)feat)[i * 2];
    float4 f1 = ((const float4*)feat)[i * 2 + 1];
    float fv[8] = {f0.x, f0.y, f0.z, f0.w, f1.x, f1.y, f1.z, f1.w};
    float r[8];
    #pragma unroll
    for (int j = 0; j < 8; ++j) {
        float t = bf2f(v[j]) * av[j] + sv[j] + fv[j];
        r[j] = t > 0.f ? t : 0.f;
    }
    float4 o0 = {r[0], r[1], r[2], r[3]};
    float4 o1 = {r[4], r[5], r[6], r[7]};
    ((float4*)out)[i * 2]     = o0;
    ((float4*)out)[i * 2 + 1] = o1;
}

extern "C" void kernel_launch(void* const* d_in, const int* in_sizes, int n_in,
                              void* d_out, int out_size, void* d_ws, size_t ws_size,
                              hipStream_t stream) {
    const float* feat = (const float*)d_in[0];
    const int*   nbr  = (const int*)d_in[1];
    const float* W1   = (const float*)d_in[2];
    const float* g1   = (const float*)d_in[3];
    const float* b1   = (const float*)d_in[4];
    const float* W2   = (const float*)d_in[5];
    const float* g2   = (const float*)d_in[6];
    const float* b2   = (const float*)d_in[7];
    float* out = (float*)d_out;

    // workspace map: [stats1 64f | stats2 64f | aff1 64f | aff2 64f | W1t | W2t | pad to 128K | bufA 128MB | bufB 128MB]
    float* stats1 = (float*)d_ws;
    float* stats2 = stats1 + 64;
    float* aff1   = stats1 + 128;
    float* aff2   = stats1 + 192;
    unsigned short* W1t = (unsigned short*)(stats1 + 256);
    unsigned short* W2t = W1t + 27648;
    unsigned short* bufA = (unsigned short*)((char*)d_ws + (1 << 17));
    unsigned short* bufB = bufA + (size_t)64000000;

    hipMemsetAsync(d_ws, 0, 512, stream);                        // zero stats1+stats2

    cvt_feat<<<31250, 256, 0, stream>>>(feat, bufA);             // feat -> bf16
    w_prep<<<216, 256, 0, stream>>>(W1, W2, W1t, W2t);           // W -> bf16 [k][co][ci]

    conv_mfma<<<6250, 256, 0, stream>>>(bufA, nbr, W1t, bufB, stats1);   // conv1 -> tmp1 + stats1
    finalize<<<1, 64, 0, stream>>>(stats1, g1, b1, aff1);
    bnrelu<<<31250, 256, 0, stream>>>(bufB, aff1, bufA);         // y1 = relu(bn1(tmp1))

    conv_mfma<<<6250, 256, 0, stream>>>(bufA, nbr, W2t, bufB, stats2);   // conv2 -> tmp2 + stats2
    finalize<<<1, 64, 0, stream>>>(stats2, g2, b2, aff2);
    final_k<<<31250, 256, 0, stream>>>(bufB, aff2, feat, out);   // relu(bn2(tmp2) + feat)
}